// Round 11
// baseline (302.210 us; speedup 1.0000x reference)
//
#include <hip/hip_runtime.h>
#include <hip/hip_bf16.h>
#include <math.h>

#define NROWS 8192
#define INDIM 768
#define TD    72
#define DM    24
#define MKEYS 8192
#define KSEL  32
#define HN    256
#define K3CAND 128

#define TWO_PI_F 6.283185307179586f

typedef __attribute__((ext_vector_type(8))) short short8_t;
typedef __attribute__((ext_vector_type(4))) float f32x4;

__device__ __forceinline__ float gelu_exact(float v){
  return 0.5f * v * (1.0f + erff(v * 0.7071067811865476f));
}

// round-to-nearest-even f32 -> bf16 bits
__device__ __forceinline__ unsigned short bf16rn(float f){
  unsigned u = __float_as_uint(f);
  unsigned r = u + 0x7FFFu + ((u >> 16) & 1u);
  return (unsigned short)(r >> 16);
}

// min across each 16-lane DPP row; lane 15 (mod 16) holds the row min.
__device__ __forceinline__ float rowmin16(float v){
  int s, p;
  s = __float_as_int(v); p = __builtin_amdgcn_update_dpp(s, s, 0x111, 0xF, 0xF, false);
  v = fminf(v, __int_as_float(p));
  s = __float_as_int(v); p = __builtin_amdgcn_update_dpp(s, s, 0x112, 0xF, 0xF, false);
  v = fminf(v, __int_as_float(p));
  s = __float_as_int(v); p = __builtin_amdgcn_update_dpp(s, s, 0x114, 0xF, 0xF, false);
  v = fminf(v, __int_as_float(p));
  s = __float_as_int(v); p = __builtin_amdgcn_update_dpp(s, s, 0x118, 0xF, 0xF, false);
  v = fminf(v, __int_as_float(p));
  return v;
}

// ---------------------------------------------------------------------------
// K0: G = FFT_256(RW[o][0:256] + i*RW[o][256:512]) panels for k5.
// ---------------------------------------------------------------------------
__global__ __launch_bounds__(256) void k0_gprep(
    const float* __restrict__ RW, float* __restrict__ Grp, float* __restrict__ Gip)
{
  __shared__ float sre[16][260];
  __shared__ float sim_[16][260];
  __shared__ float twc[HN], tws[HN];
  const int t = threadIdx.x;
  const int o0 = blockIdx.x * 16;
  {
    const float a = (float)t * (TWO_PI_F / 256.f);
    twc[t] = cosf(a); tws[t] = sinf(a);
  }
  const int r = t >> 4, cg = t & 15;
  const int o = o0 + r;
#pragma unroll
  for (int j = 0; j < 16; j++) {
    const int n = cg + 16 * j;
    const int hb = __brev((unsigned)n) >> 24;
    float cr = 0.f, ci = 0.f;
    if (o < TD) { cr = RW[(size_t)o * 512 + n]; ci = RW[(size_t)o * 512 + 256 + n]; }
    sre[r][hb] = cr; sim_[r][hb] = ci;
  }
  __syncthreads();
  const int t16 = t & 15;
  for (int s = 0; s < 8; s++) {
    const int half = 1 << s;
#pragma unroll
    for (int p = 0; p < 8; p++) {
      const int bi = t16 + 16 * p;
      const int jj = bi & (half - 1);
      const int base = (bi >> s) << (s + 1);
      const int i0 = base + jj, i1 = i0 + half;
      const int tw = jj << (7 - s);
      const float wr = twc[tw], wi = -tws[tw];
      const float ar = sre[r][i0], ai = sim_[r][i0];
      const float br = sre[r][i1], b2 = sim_[r][i1];
      const float tr = wr * br - wi * b2, ti = wr * b2 + wi * br;
      sre[r][i0] = ar + tr; sim_[r][i0] = ai + ti;
      sre[r][i1] = ar - tr; sim_[r][i1] = ai - ti;
    }
    __syncthreads();
  }
#pragma unroll
  for (int p = 0; p < 16; p++) {
    const int h = t16 + 16 * p;
    const size_t base = ((size_t)(h >> 2) * 128 + o) * 4 + (h & 3);
    Grp[base] = sre[r][h];
    Gip[base] = sim_[r][h];
  }
}

// ---------------------------------------------------------------------------
// KW: split key_phase_W (256x768) into bf16 hi/lo panels.
// ---------------------------------------------------------------------------
__global__ __launch_bounds__(256) void kw_split(
    const float* __restrict__ Wp, unsigned short* __restrict__ Wphi,
    unsigned short* __restrict__ Wplo)
{
  const int i4 = blockIdx.x * 256 + threadIdx.x;
  const float4 v = ((const float4*)Wp)[i4];
  float vv[4] = {v.x, v.y, v.z, v.w};
  ushort4 hh, ll;
  unsigned short* hp = (unsigned short*)&hh;
  unsigned short* lp = (unsigned short*)&ll;
#pragma unroll
  for (int j = 0; j < 4; j++) {
    const unsigned short h = bf16rn(vv[j]);
    const float hf = __uint_as_float(((unsigned)h) << 16);
    hp[j] = h; lp[j] = bf16rn(vv[j] - hf);
  }
  ((ushort4*)Wphi)[i4] = hh;
  ((ushort4*)Wplo)[i4] = ll;
}

// ---------------------------------------------------------------------------
// KWO: split W_out (768x72) into zero-padded 768x96 bf16 hi/lo panels.
// ---------------------------------------------------------------------------
__global__ __launch_bounds__(256) void kwo_split(
    const float* __restrict__ Wo, unsigned short* __restrict__ Wohi,
    unsigned short* __restrict__ Wolo)
{
  const int idx = blockIdx.x * 256 + threadIdx.x;   // 768*96 = 73728, grid 288
  const int row = idx / 96, k = idx % 96;
  const float v = (k < TD) ? Wo[(size_t)row * TD + k] : 0.f;
  const unsigned short h = bf16rn(v);
  const float hf = __uint_as_float(((unsigned)h) << 16);
  Wohi[idx] = h;
  Wolo[idx] = bf16rn(v - hf);
}

// ---------------------------------------------------------------------------
// K1 (fp32 — q is SELECTION-CRITICAL: keep this exact fmaf chain).
// ---------------------------------------------------------------------------
__global__ __launch_bounds__(256) void k1_encode(
    const float* __restrict__ x, const float* __restrict__ Wi,
    const float* __restrict__ bi, const float* __restrict__ gi,
    const float* __restrict__ bbi, const float* __restrict__ ricci,
    float* __restrict__ qvec, float* __restrict__ qnorm)
{
  __shared__ float xs[16][132];
  __shared__ float Ws[TD][132];
  __shared__ float zs[16][73];
  __shared__ float zb[16][25];
  const int t = threadIdx.x;
  const int r2 = t >> 4, ks = (t >> 3) & 1, u = t & 7;
  const int row0 = blockIdx.x * 16;

  float acc[9];
#pragma unroll
  for (int j = 0; j < 9; j++) acc[j] = 0.f;

  for (int kc = 0; kc < 6; kc++) {
    __syncthreads();
#pragma unroll
    for (int i = 0; i < 2; i++) {
      int idx = t + 256 * i;
      int rr = idx >> 5, kk = (idx & 31) << 2;
      *(float4*)&xs[rr][kk] = *(const float4*)&x[(size_t)(row0 + rr) * INDIM + kc * 128 + kk];
    }
#pragma unroll
    for (int i = 0; i < 9; i++) {
      int idx = t + 256 * i;
      int rr = idx >> 5, kk = (idx & 31) << 2;
      *(float4*)&Ws[rr][kk] = *(const float4*)&Wi[(size_t)rr * INDIM + kc * 128 + kk];
    }
    __syncthreads();
    const int kb = ks * 64;
#pragma unroll 4
    for (int kq = 0; kq < 16; kq++) {
      const float4 xv = *(const float4*)&xs[r2][kb + kq * 4];
#pragma unroll
      for (int j = 0; j < 9; j++) {
        const float4 wv = *(const float4*)&Ws[u + 8 * j][kb + kq * 4];
        acc[j] = fmaf(xv.x, wv.x, fmaf(xv.y, wv.y, fmaf(xv.z, wv.z, fmaf(xv.w, wv.w, acc[j]))));
      }
    }
  }
#pragma unroll
  for (int j = 0; j < 9; j++) acc[j] += __shfl_xor(acc[j], 8);

  float yv[9];
  float ps = 0.f, pq = 0.f;
#pragma unroll
  for (int j = 0; j < 9; j++) {
    const int o = u + 8 * j;
    yv[j] = acc[j] + bi[o];
    ps += yv[j]; pq += yv[j] * yv[j];
  }
#pragma unroll
  for (int m = 1; m < 8; m <<= 1) { ps += __shfl_xor(ps, m); pq += __shfl_xor(pq, m); }
  const float mean = ps * (1.f / 72.f);
  const float var  = pq * (1.f / 72.f) - mean * mean;
  const float rstd = rsqrtf(var + 1e-5f);
#pragma unroll
  for (int j = 0; j < 9; j++) {
    const int o = u + 8 * j;
    const float z = gelu_exact((yv[j] - mean) * rstd * gi[o] + bbi[o]);
    if (ks == 0) zs[r2][o] = z;
  }
  __syncthreads();
  {
    const int kt = t & 15;
    for (int e = kt; e < 24; e += 16)
      zb[r2][e] = (zs[r2][3 * e] + zs[r2][3 * e + 1] + zs[r2][3 * e + 2]) * (1.f / 3.f);
  }
  __syncthreads();
  {
    const int kt = t & 15;
    float qnp = 0.f;
    for (int d = kt; d < 24; d += 16) {
      float qd = 0.f;
#pragma unroll
      for (int e = 0; e < 24; e++) qd = fmaf(zb[r2][e], ricci[e * 24 + d], qd);
      qvec[(size_t)(row0 + r2) * DM + d] = qd;
      qnp = fmaf(qd, qd, qnp);
    }
#pragma unroll
    for (int m = 1; m < 16; m <<= 1) qnp += __shfl_xor(qnp, m, 16);
    if (kt == 0) qnorm[row0 + r2] = qnp;
  }
}

// ---------------------------------------------------------------------------
// K2: key norms + quantum-phase means + bf16 hi/lo split keys + chunk kn-max
// ---------------------------------------------------------------------------
__global__ __launch_bounds__(256) void k2_prep(
    const float* __restrict__ keys, const float* __restrict__ qp,
    float* __restrict__ kn, float* __restrict__ pm,
    unsigned short* __restrict__ khi, unsigned short* __restrict__ klo,
    float* __restrict__ kmx)
{
  __shared__ float red[256];
  const int t = threadIdx.x;
  const int m = blockIdx.x * 256 + t;
  float kv[24];
#pragma unroll
  for (int d = 0; d < DM; d += 4) {
    const float4 v = *(const float4*)&keys[(size_t)m * DM + d];
    kv[d] = v.x; kv[d + 1] = v.y; kv[d + 2] = v.z; kv[d + 3] = v.w;
  }
  float s = 0.f;
#pragma unroll
  for (int d = 0; d < DM; d++) s = fmaf(kv[d], kv[d], s);
  kn[m] = s;
  float p = 0.f;
#pragma unroll
  for (int q = 0; q < 8; q++) p += tanhf(qp[(size_t)m * 8 + q]);
  pm[m] = p * 0.125f;
#pragma unroll
  for (int d = 0; d < DM; d++) {
    const unsigned short h = bf16rn(kv[d]);
    const float hf = __uint_as_float(((unsigned)h) << 16);
    const unsigned short l = bf16rn(kv[d] - hf);
    khi[(size_t)m * 32 + d] = h;
    klo[(size_t)m * 32 + d] = l;
  }
#pragma unroll
  for (int d = DM; d < 32; d++) { khi[(size_t)m * 32 + d] = 0; klo[(size_t)m * 32 + d] = 0; }
  red[t] = s;
  __syncthreads();
  for (int off = 128; off > 0; off >>= 1) {
    if (t < off) red[t] = fmaxf(red[t], red[t + off]);
    __syncthreads();
  }
  if (t == 0) kmx[blockIdx.x] = red[0];
}

// ---------------------------------------------------------------------------
// K3 v7: MFMA screening + exact fp32 finish. 16 rows/block (single MFMA
// row-tile), 1024 thr, grid 512 -> 2 blocks/CU = 32 waves/CU (2x occupancy
// vs v5). Loads are the v5 (non-prefetched) form — v6's register prefetch
// spilled to scratch (VGPR stuck at 64, FETCH 4x). Per-row arithmetic chain
// bit-identical to v5 -> identical selection -> identical output.
// ---------------------------------------------------------------------------
__global__ __launch_bounds__(1024, 8) void k3_topk(
    const float* __restrict__ qvec, const float* __restrict__ qnorm,
    const float* __restrict__ keys, const float* __restrict__ kn,
    const unsigned short* __restrict__ khi, const unsigned short* __restrict__ klo,
    const float* __restrict__ kmx,
    const float* __restrict__ fw,  const float* __restrict__ pm,
    float* __restrict__ w_out, int* __restrict__ itop_out, float* __restrict__ gain_out)
{
  __shared__ float qsm[16][25];
  __shared__ float qns[16];
  __shared__ unsigned short qh_l[16][32];
  __shared__ unsigned short ql_l[16][32];
  __shared__ float gmins[64][17];
  __shared__ float Ts[16];
  __shared__ float Tm2s[16];
  __shared__ unsigned glive[2];
  __shared__ int cnt[16];
  __shared__ int      candI[16][K3CAND];
  __shared__ unsigned candV[16][K3CAND];
  __shared__ float wV[16][KSEL];
  __shared__ int   wI[16][KSEL];
  __shared__ float knmax_s;

  const int t = threadIdx.x;
  const int w = t >> 6, lane = t & 63;
  const int colid = lane & 15;
  const int kgrp  = lane >> 4;
  const int row0 = blockIdx.x * 16;

  if (t < 16 * DM) qsm[t / DM][t % DM] = qvec[(size_t)row0 * DM + t];
  if (t < 16) { qns[t] = qnorm[row0 + t]; cnt[t] = 0; }
  if (t < 2) glive[t] = 0u;
  if (t == 0) { float m = 0.f; for (int i = 0; i < 32; i++) m = fmaxf(m, kmx[i]); knmax_s = m; }
  __syncthreads();
  if (t < 512) {
    const int r = t >> 5, k = t & 31;
    const float v = (k < DM) ? qsm[r][k] : 0.f;
    const unsigned short h = bf16rn(v);
    const float hf = __uint_as_float(((unsigned)h) << 16);
    qh_l[r][k] = h;
    ql_l[r][k] = bf16rn(v - hf);
  }
  __syncthreads();

  const short8_t ah0 = *(const short8_t*)&qh_l[colid][kgrp * 8];
  const short8_t al0 = *(const short8_t*)&ql_l[colid][kgrp * 8];
  float qn4[4];
#pragma unroll
  for (int reg = 0; reg < 4; reg++) qn4[reg] = qns[kgrp * 4 + reg];

  // ---- pass A: approx group minima (rows 0-15; same MFMA order as v5's c0) ----
  for (int u = 0; u < 4; u++) {
    const int g = w + 16 * u;
    const int nbase = g * 128;
    float mn[4];
#pragma unroll
    for (int j = 0; j < 8; j++) {
      const int key = nbase + j * 16 + colid;
      const short8_t bh = *(const short8_t*)&khi[(size_t)key * 32 + kgrp * 8];
      const short8_t bl = *(const short8_t*)&klo[(size_t)key * 32 + kgrp * 8];
      const float knv = kn[key];
      f32x4 c0 = {0.f, 0.f, 0.f, 0.f};
      c0 = __builtin_amdgcn_mfma_f32_16x16x32_bf16(ah0, bh, c0, 0, 0, 0);
      c0 = __builtin_amdgcn_mfma_f32_16x16x32_bf16(ah0, bl, c0, 0, 0, 0);
      c0 = __builtin_amdgcn_mfma_f32_16x16x32_bf16(al0, bh, c0, 0, 0, 0);
#pragma unroll
      for (int reg = 0; reg < 4; reg++) {
        const float d0 = fmaf(-2.f, c0[reg], qn4[reg] + knv);
        if (j == 0) mn[reg] = d0;
        else        mn[reg] = fminf(mn[reg], d0);
      }
    }
#pragma unroll
    for (int reg = 0; reg < 4; reg++) {
      const float v0 = rowmin16(mn[reg]);
      if (colid == 15) gmins[g][kgrp * 4 + reg] = v0;
    }
  }
  __syncthreads();

  // ---- threshold: 32nd smallest approx group-min per row + margin ----
  {
    const int r = t & 15, i = t >> 4;    // i in [0,64): one group each
    const float v0 = gmins[i][r];
    int rk0 = 0, eq0 = 0;
    for (int g = 0; g < 64; g++) {
      const float gv = gmins[g][r];
      rk0 += (gv < v0); eq0 += (gv == v0);
    }
    if (rk0 <= 31 && rk0 + eq0 > 31) Ts[r] = v0;
  }
  __syncthreads();
  if (t < 16) {
    const float T = Ts[t];
    const float mu = 2e-4f * sqrtf(fmaxf(qns[t], 0.f) * knmax_s) + 1e-6f;
    Tm2s[t] = T + fabsf(T) * 1e-6f + 2.f * mu;
  }
  __syncthreads();
  {
    const int r = t & 15, i = t >> 4;
    if (gmins[i][r] <= Tm2s[r]) atomicOr(&glive[i >> 5], 1u << (i & 31));
  }
  __syncthreads();

  float tm4[4];
#pragma unroll
  for (int reg = 0; reg < 4; reg++) tm4[reg] = Tm2s[kgrp * 4 + reg];

  // ---- pass B: recompute live groups, filter, collect candidate indices ----
  for (int u = 0; u < 4; u++) {
    const int g = w + 16 * u;
    if (!((glive[g >> 5] >> (g & 31)) & 1u)) continue;
    const int nbase = g * 128;
#pragma unroll
    for (int j = 0; j < 8; j++) {
      const int key = nbase + j * 16 + colid;
      const short8_t bh = *(const short8_t*)&khi[(size_t)key * 32 + kgrp * 8];
      const short8_t bl = *(const short8_t*)&klo[(size_t)key * 32 + kgrp * 8];
      const float knv = kn[key];
      f32x4 c0 = {0.f, 0.f, 0.f, 0.f};
      c0 = __builtin_amdgcn_mfma_f32_16x16x32_bf16(ah0, bh, c0, 0, 0, 0);
      c0 = __builtin_amdgcn_mfma_f32_16x16x32_bf16(ah0, bl, c0, 0, 0, 0);
      c0 = __builtin_amdgcn_mfma_f32_16x16x32_bf16(al0, bh, c0, 0, 0, 0);
#pragma unroll
      for (int reg = 0; reg < 4; reg++) {
        const float d0 = fmaf(-2.f, c0[reg], qn4[reg] + knv);
        if (d0 <= tm4[reg]) {
          const int row = kgrp * 4 + reg;
          const int pos = atomicAdd(&cnt[row], 1);
          if (pos < K3CAND) candI[row][pos] = key;
        }
      }
    }
  }
  for (int idx = t; idx < 16 * KSEL; idx += 1024) { wV[idx >> 5][idx & 31] = 1e30f; wI[idx >> 5][idx & 31] = 0; }
  __syncthreads();

  // ---- exact fp32 recompute of candidates (round-1 chain) ----
  {
    const int r = t >> 6, kt = t & 63;   // 16 rows x 64 threads
    const int C = min(cnt[r], K3CAND);
    const float qnr = qns[r];
    for (int ci = kt; ci < C; ci += 64) {
      const int key = candI[r][ci];
      float kv[24];
#pragma unroll
      for (int d = 0; d < DM; d += 4) {
        const float4 v = *(const float4*)&keys[(size_t)key * DM + d];
        kv[d] = v.x; kv[d + 1] = v.y; kv[d + 2] = v.z; kv[d + 3] = v.w;
      }
      float dot = 0.f;
#pragma unroll
      for (int d = 0; d < DM; d++) dot = fmaf(kv[d], qsm[r][d], dot);
      const float d2 = fmaf(-2.f, dot, qnr + kn[key]);
      candV[r][ci] = __float_as_uint(fmaxf(d2, 0.f));
    }
  }
  __syncthreads();

  // ---- exact rank-select top-32 ----
  {
    const int r = t >> 6, kt = t & 63;
    const int C = min(cnt[r], K3CAND);
    for (int ci = kt; ci < C; ci += 64) {
      const unsigned v = candV[r][ci];
      const unsigned key = (unsigned)candI[r][ci];
      int rk = 0;
      for (int j = 0; j < C; j++) {
        const unsigned vj = candV[r][j];
        rk += (vj < v) || (vj == v && (unsigned)candI[r][j] < key);
      }
      if (rk < KSEL) { wV[r][rk] = __uint_as_float(v); wI[r][rk] = (int)key; }
    }
  }
  __syncthreads();

  // ---- softmax over -dist, gain ----
  float sc;
  {
    const float f0 = fw[0], f1 = fw[1], f2 = fw[2], f3 = fw[3];
    const float mx = fmaxf(fmaxf(f0, f1), fmaxf(f2, f3));
    const float e0 = expf(f0 - mx), e1 = expf(f1 - mx), e2 = expf(f2 - mx), e3 = expf(f3 - mx);
    sc = (e0 + 0.5f * e1 + 0.25f * e2 + 0.125f * e3) / (e0 + e1 + e2 + e3);
  }
  if (t < 256) {
    const int r = t >> 4, kt = t & 15;
    const float dA = sqrtf(wV[r][kt]) * sc;
    const float dB = sqrtf(wV[r][kt + 16]) * sc;
    float mn = fminf(dA, dB);
#pragma unroll
    for (int m = 1; m < 16; m <<= 1) mn = fminf(mn, __shfl_xor(mn, m, 16));
    const float eA = expf(mn - dA), eB = expf(mn - dB);
    float s = eA + eB;
#pragma unroll
    for (int m = 1; m < 16; m <<= 1) s += __shfl_xor(s, m, 16);
    const float w0 = eA / s, w1 = eB / s;
    const int k0 = wI[r][kt], k1 = wI[r][kt + 16];
    float gp = w0 * pm[k0] + w1 * pm[k1];
#pragma unroll
    for (int m = 1; m < 16; m <<= 1) gp += __shfl_xor(gp, m, 16);
    const size_t row = (size_t)(row0 + r);
    w_out[row * KSEL + kt] = w0;      w_out[row * KSEL + kt + 16] = w1;
    itop_out[row * KSEL + kt] = k0;   itop_out[row * KSEL + kt + 16] = k1;
    if (kt == 0) gain_out[row] = 1.f + 0.02f * gp;
  }
}

// ---------------------------------------------------------------------------
// K4a: p = x@Wp.T + bp via MFMA. (unchanged)
// ---------------------------------------------------------------------------
__global__ __launch_bounds__(512) void k4a_pgemm(
    const float* __restrict__ x, const unsigned short* __restrict__ Wphi,
    const unsigned short* __restrict__ Wplo, const float* __restrict__ bp,
    float* __restrict__ p)
{
  const int t = threadIdx.x;
  const int w = t >> 6, lane = t & 63;
  const int colid = lane & 15, kgrp = lane >> 4;
  const int wm = w >> 2, wn = w & 3;
  const int row0 = blockIdx.x * 32;
  const int arow = row0 + wm * 16 + colid;

  f32x4 acc0 = {0.f, 0.f, 0.f, 0.f};
  f32x4 acc1 = {0.f, 0.f, 0.f, 0.f};
  f32x4 acc2 = {0.f, 0.f, 0.f, 0.f};
  f32x4 acc3 = {0.f, 0.f, 0.f, 0.f};

  for (int kc = 0; kc < 24; kc++) {
    const int kb = kc * 32 + kgrp * 8;
    float xv[8];
    *(float4*)&xv[0] = *(const float4*)&x[(size_t)arow * INDIM + kb];
    *(float4*)&xv[4] = *(const float4*)&x[(size_t)arow * INDIM + kb + 4];
    short8_t ah, al;
#pragma unroll
    for (int i = 0; i < 8; i++) {
      const unsigned short h = bf16rn(xv[i]);
      const float hf = __uint_as_float(((unsigned)h) << 16);
      ah[i] = (short)h;
      al[i] = (short)bf16rn(xv[i] - hf);
    }
#pragma unroll
    for (int ct = 0; ct < 4; ct++) {
      const int col = wn * 64 + ct * 16 + colid;
      const short8_t bh = *(const short8_t*)&Wphi[(size_t)col * INDIM + kb];
      const short8_t bl = *(const short8_t*)&Wplo[(size_t)col * INDIM + kb];
      f32x4* pa = (ct == 0) ? &acc0 : (ct == 1) ? &acc1 : (ct == 2) ? &acc2 : &acc3;
      *pa = __builtin_amdgcn_mfma_f32_16x16x32_bf16(ah, bh, *pa, 0, 0, 0);
      *pa = __builtin_amdgcn_mfma_f32_16x16x32_bf16(al, bh, *pa, 0, 0, 0);
      *pa = __builtin_amdgcn_mfma_f32_16x16x32_bf16(ah, bl, *pa, 0, 0, 0);
    }
  }
#pragma unroll
  for (int ct = 0; ct < 4; ct++) {
    const int col = wn * 64 + ct * 16 + colid;
    const float b = bp[col];
    const f32x4 a = (ct == 0) ? acc0 : (ct == 1) ? acc1 : (ct == 2) ? acc2 : acc3;
#pragma unroll
    for (int reg = 0; reg < 4; reg++) {
      const int row = row0 + wm * 16 + kgrp * 4 + reg;
      p[(size_t)row * HN + col] = a[reg] + b;
    }
  }
}

// ---------------------------------------------------------------------------
// K4b: Kf = FFT(e^{i 2pi sigmoid(p)}) * e^{i ek}. (unchanged)
// ---------------------------------------------------------------------------
__global__ __launch_bounds__(256) void k4b_fft(
    const float* __restrict__ p, const float* __restrict__ ek,
    float* __restrict__ kf_re, float* __restrict__ kf_im)
{
  __shared__ float2 c[16][273];
  __shared__ float twc[HN], tws[HN];
  const int t = threadIdx.x;
  const int row0 = blockIdx.x * 16;
  {
    const float a = (float)t * (TWO_PI_F / 256.f);
    twc[t] = cosf(a); tws[t] = sinf(a);
  }
  {
    const int hb = __brev((unsigned)t) >> 24;
    const int hbi = hb + (hb >> 5);
#pragma unroll
    for (int i = 0; i < 16; i++) {
      const float pv = p[(size_t)(row0 + i) * HN + t];
      const float sg = 1.f / (1.f + expf(-pv));
      float sn, cs;
      __sincosf(TWO_PI_F * sg, &sn, &cs);
      c[i][hbi] = make_float2(cs, sn);
    }
  }
  __syncthreads();
  const int r = t >> 4, t16 = t & 15;
  for (int s = 0; s < 8; s++) {
    const int half = 1 << s;
#pragma unroll
    for (int pp = 0; pp < 8; pp++) {
      const int bi = t16 + 16 * pp;
      const int jj = bi & (half - 1);
      const int base = (bi >> s) << (s + 1);
      const int i0 = base + jj, i1 = i0 + half;
      const int tw = jj << (7 - s);
      const float wr = twc[tw], wi = -tws[tw];
      const int p0 = i0 + (i0 >> 5), p1 = i1 + (i1 >> 5);
      const float2 A = c[r][p0];
      const float2 B = c[r][p1];
      const float tr = wr * B.x - wi * B.y, ti = wr * B.y + wi * B.x;
      c[r][p0] = make_float2(A.x + tr, A.y + ti);
      c[r][p1] = make_float2(A.x - tr, A.y - ti);
    }
    __syncthreads();
  }
  {
    float esn, ecs;
    __sincosf(ek[t], &esn, &ecs);
    const int ti = t + (t >> 5);
#pragma unroll
    for (int i = 0; i < 16; i++) {
      const float2 v = c[i][ti];
      const size_t o = (size_t)(row0 + i) * HN + t;
      kf_re[o] = v.x * ecs - v.y * esn;
      kf_im[o] = v.x * esn + v.y * ecs;
    }
  }
}

// ---------------------------------------------------------------------------
// K5 v2: gather + Y = conj(Kf)*Hmix, then triplet = rb + (Y . G)/256. (unchanged)
// ---------------------------------------------------------------------------
__global__ __launch_bounds__(256) void k5_holo(
    const float* __restrict__ holo_re, const float* __restrict__ holo_im,
    const float* __restrict__ kf_re, const float* __restrict__ kf_im,
    const float* __restrict__ w_ws, const int* __restrict__ itop_ws,
    const float* __restrict__ Grp, const float* __restrict__ Gip,
    const float* __restrict__ rb, float* __restrict__ triplet)
{
  __shared__ __align__(16) float ysr[8][260];
  __shared__ __align__(16) float ysi[8][260];
  __shared__ float red[4][8][128];
  __shared__ float wsm[8][KSEL];
  __shared__ int   ism[8][KSEL];
  const int t = threadIdx.x;
  const int w = t >> 6, lane = t & 63;
  const int row0 = blockIdx.x * 8;

  {
    const int rr = t >> 5, k2 = t & 31;
    wsm[rr][k2] = w_ws[(size_t)(row0 + rr) * KSEL + k2];
    ism[rr][k2] = itop_ws[(size_t)(row0 + rr) * KSEL + k2];
  }
  __syncthreads();

#pragma unroll
  for (int pass = 0; pass < 2; pass++) {
    const int row = w + 4 * pass;
    float4 hr4 = {0.f, 0.f, 0.f, 0.f};
    float4 hi4 = {0.f, 0.f, 0.f, 0.f};
#pragma unroll 8
    for (int k2 = 0; k2 < KSEL; k2++) {
      const int m = ism[row][k2];
      const float wk = wsm[row][k2];
      const float4 re4 = *(const float4*)&holo_re[(size_t)m * HN + lane * 4];
      const float4 im4 = *(const float4*)&holo_im[(size_t)m * HN + lane * 4];
      hr4.x = fmaf(wk, re4.x, hr4.x); hr4.y = fmaf(wk, re4.y, hr4.y);
      hr4.z = fmaf(wk, re4.z, hr4.z); hr4.w = fmaf(wk, re4.w, hr4.w);
      hi4.x = fmaf(wk, im4.x, hi4.x); hi4.y = fmaf(wk, im4.y, hi4.y);
      hi4.z = fmaf(wk, im4.z, hi4.z); hi4.w = fmaf(wk, im4.w, hi4.w);
    }
    const size_t o = (size_t)(row0 + row) * HN + lane * 4;
    const float4 kr4 = *(const float4*)&kf_re[o];
    const float4 ki4 = *(const float4*)&kf_im[o];
    float4 yr4, yi4;
    yr4.x = kr4.x * hr4.x + ki4.x * hi4.x;  yi4.x = kr4.x * hi4.x - ki4.x * hr4.x;
    yr4.y = kr4.y * hr4.y + ki4.y * hi4.y;  yi4.y = kr4.y * hi4.y - ki4.y * hr4.y;
    yr4.z = kr4.z * hr4.z + ki4.z * hi4.z;  yi4.z = kr4.z * hi4.z - ki4.z * hr4.z;
    yr4.w = kr4.w * hr4.w + ki4.w * hi4.w;  yi4.w = kr4.w * hi4.w - ki4.w * hr4.w;
    *(float4*)&ysr[row][lane * 4] = yr4;
    *(float4*)&ysi[row][lane * 4] = yi4;
  }
  __syncthreads();

  float acc[8][2];
#pragma unroll
  for (int rr = 0; rr < 8; rr++) { acc[rr][0] = 0.f; acc[rr][1] = 0.f; }
#pragma unroll 4
  for (int i = 0; i < 16; i++) {
    const int h4 = w * 16 + i;
    const float4 gra = *(const float4*)&Grp[((size_t)h4 * 128 + lane) * 4];
    const float4 gia = *(const float4*)&Gip[((size_t)h4 * 128 + lane) * 4];
    const float4 grb = *(const float4*)&Grp[((size_t)h4 * 128 + 64 + lane) * 4];
    const float4 gib = *(const float4*)&Gip[((size_t)h4 * 128 + 64 + lane) * 4];
#pragma unroll
    for (int rr = 0; rr < 8; rr++) {
      const float4 yr4 = *(const float4*)&ysr[rr][h4 * 4];
      const float4 yi4 = *(const float4*)&ysi[rr][h4 * 4];
      acc[rr][0] = fmaf(yr4.x, gra.x, fmaf(yr4.y, gra.y, fmaf(yr4.z, gra.z, fmaf(yr4.w, gra.w, acc[rr][0]))));
      acc[rr][0] = fmaf(yi4.x, gia.x, fmaf(yi4.y, gia.y, fmaf(yi4.z, gia.z, fmaf(yi4.w, gia.w, acc[rr][0]))));
      acc[rr][1] = fmaf(yr4.x, grb.x, fmaf(yr4.y, grb.y, fmaf(yr4.z, grb.z, fmaf(yr4.w, grb.w, acc[rr][1]))));
      acc[rr][1] = fmaf(yi4.x, gib.x, fmaf(yi4.y, gib.y, fmaf(yi4.z, gib.z, fmaf(yi4.w, gib.w, acc[rr][1]))));
    }
  }
#pragma unroll
  for (int rr = 0; rr < 8; rr++) {
    red[w][rr][lane] = acc[rr][0];
    red[w][rr][64 + lane] = acc[rr][1];
  }
  __syncthreads();

  for (int idx = t; idx < 8 * 128; idx += 256) {
    const int rr = idx >> 7, o = idx & 127;
    if (o < TD) {
      const float s = red[0][rr][o] + red[1][rr][o] + red[2][rr][o] + red[3][rr][o];
      triplet[(size_t)(row0 + rr) * TD + o] = rb[o] + s * (1.f / 256.f);
    }
  }
}

// ---------------------------------------------------------------------------
// K6 v2 (MFMA): out = gelu(LN(triplet@W_out.T + b_out)) * gain. (unchanged)
// ---------------------------------------------------------------------------
__global__ __launch_bounds__(256) void k6_mfma(
    const float* __restrict__ triplet, const unsigned short* __restrict__ Wohi,
    const unsigned short* __restrict__ Wolo, const float* __restrict__ bo,
    const float* __restrict__ go, const float* __restrict__ bbo,
    const float* __restrict__ gain, float* __restrict__ out)
{
  __shared__ float ys[16][772];
  const int t = threadIdx.x;
  const int w = t >> 6, lane = t & 63;
  const int colid = lane & 15, kgrp = lane >> 4;
  const int row0 = blockIdx.x * 16;
  const int arow = row0 + colid;

  f32x4 acc[12];
#pragma unroll
  for (int ct = 0; ct < 12; ct++) acc[ct] = (f32x4){0.f, 0.f, 0.f, 0.f};

#pragma unroll
  for (int kc = 0; kc < 3; kc++) {
    const int kb = kc * 32 + kgrp * 8;
    float xv[8];
    if (kb < TD) {
      *(float4*)&xv[0] = *(const float4*)&triplet[(size_t)arow * TD + kb];
      *(float4*)&xv[4] = *(const float4*)&triplet[(size_t)arow * TD + kb + 4];
    } else {
#pragma unroll
      for (int i = 0; i < 8; i++) xv[i] = 0.f;
    }
    short8_t ah, al;
#pragma unroll
    for (int i = 0; i < 8; i++) {
      const unsigned short h = bf16rn(xv[i]);
      const float hf = __uint_as_float(((unsigned)h) << 16);
      ah[i] = (short)h; al[i] = (short)bf16rn(xv[i] - hf);
    }
#pragma unroll
    for (int ct = 0; ct < 12; ct++) {
      const int col = w * 192 + ct * 16 + colid;
      const short8_t bh = *(const short8_t*)&Wohi[(size_t)col * 96 + kb];
      const short8_t bl = *(const short8_t*)&Wolo[(size_t)col * 96 + kb];
      acc[ct] = __builtin_amdgcn_mfma_f32_16x16x32_bf16(ah, bh, acc[ct], 0, 0, 0);
      acc[ct] = __builtin_amdgcn_mfma_f32_16x16x32_bf16(al, bh, acc[ct], 0, 0, 0);
      acc[ct] = __builtin_amdgcn_mfma_f32_16x16x32_bf16(ah, bl, acc[ct], 0, 0, 0);
    }
  }
#pragma unroll
  for (int ct = 0; ct < 12; ct++) {
    const int col = w * 192 + ct * 16 + colid;
    const float b = bo[col];
#pragma unroll
    for (int reg = 0; reg < 4; reg++)
      ys[kgrp * 4 + reg][col] = acc[ct][reg] + b;
  }
  __syncthreads();

  const int r = t >> 4, kt = t & 15;
  float s = 0.f, sq = 0.f;
  for (int u = 0; u < 48; u++) {
    const float v = ys[r][kt + 16 * u];
    s += v; sq = fmaf(v, v, sq);
  }
#pragma unroll
  for (int m = 1; m < 16; m <<= 1) { s += __shfl_xor(s, m, 16); sq += __shfl_xor(sq, m, 16); }
  const float mean = s * (1.f / 768.f);
  const float var  = sq * (1.f / 768.f) - mean * mean;
  const float rstd = rsqrtf(var + 1e-5f);
  const float gn = gain[row0 + r];
  for (int u = 0; u < 48; u++) {
    const int e = kt + 16 * u;
    const float v = (ys[r][e] - mean) * rstd * go[e] + bbo[e];
    out[(size_t)(row0 + r) * INDIM + e] = gelu_exact(v) * gn;
  }
}

// ---------------------------------------------------------------------------
extern "C" void kernel_launch(void* const* d_in, const int* in_sizes, int n_in,
                              void* d_out, int out_size, void* d_ws, size_t ws_size,
                              hipStream_t stream)
{
  (void)in_sizes; (void)n_in; (void)out_size; (void)ws_size;
  const float* x     = (const float*)d_in[0];
  const float* Wi    = (const float*)d_in[1];
  const float* bi    = (const float*)d_in[2];
  const float* gi    = (const float*)d_in[3];
  const float* bbi   = (const float*)d_in[4];
  const float* ricci = (const float*)d_in[5];
  const float* fw    = (const float*)d_in[6];
  const float* keys  = (const float*)d_in[7];
  const float* Wp    = (const float*)d_in[8];
  const float* bp    = (const float*)d_in[9];
  const float* ek    = (const float*)d_in[10];
  const float* hre   = (const float*)d_in[11];
  const float* him   = (const float*)d_in[12];
  const float* RW    = (const float*)d_in[13];
  const float* rb    = (const float*)d_in[14];
  const float* Wo    = (const float*)d_in[15];
  const float* bo    = (const float*)d_in[16];
  const float* go    = (const float*)d_in[17];
  const float* bbo   = (const float*)d_in[18];
  const float* qp    = (const float*)d_in[19];
  float* out = (float*)d_out;

  char* ws = (char*)d_ws;
  float* qvec    = (float*)(ws + 0);
  float* qnorm   = (float*)(ws + 786432);
  float* kn      = (float*)(ws + 819200);
  float* pm      = (float*)(ws + 851968);
  float* gain    = (float*)(ws + 884736);
  float* w_ws    = (float*)(ws + 917504);
  int*   itop    = (int*)  (ws + 1966080);
  float* triplet = (float*)(ws + 3014656);
  float* kf_re   = (float*)(ws + 5373952);
  float* kf_im   = (float*)(ws + 13762560);
  unsigned short* khi = (unsigned short*)(ws + 22151168);  // 524288
  unsigned short* klo = (unsigned short*)(ws + 22675456);  // 524288
  float* kmx     = (float*)(ws + 23199744);                // 1 KB
  float* Grp     = (float*)(ws + 23200768);                // 131072
  float* Gip     = (float*)(ws + 23331840);                // 131072
  unsigned short* Wphi = (unsigned short*)(ws + 23462912); // 393216
  unsigned short* Wplo = (unsigned short*)(ws + 23856128); // 393216
  float* pbuf    = (float*)(ws + 24249344);                // 8388608
  unsigned short* Wohi = (unsigned short*)(ws + 32637952); // 147456
  unsigned short* Wolo = (unsigned short*)(ws + 32785408); // 147456 -> ends 32932864

  k0_gprep<<<dim3(8), dim3(256), 0, stream>>>(RW, Grp, Gip);
  kw_split<<<dim3(192), dim3(256), 0, stream>>>(Wp, Wphi, Wplo);
  kwo_split<<<dim3(288), dim3(256), 0, stream>>>(Wo, Wohi, Wolo);
  k2_prep<<<dim3(MKEYS / 256), dim3(256), 0, stream>>>(keys, qp, kn, pm, khi, klo, kmx);
  k1_encode<<<dim3(NROWS / 16), dim3(256), 0, stream>>>(x, Wi, bi, gi, bbi, ricci, qvec, qnorm);
  k4a_pgemm<<<dim3(NROWS / 32), dim3(512), 0, stream>>>(x, Wphi, Wplo, bp, pbuf);
  k4b_fft<<<dim3(NROWS / 16), dim3(256), 0, stream>>>(pbuf, ek, kf_re, kf_im);
  k3_topk<<<dim3(NROWS / 16), dim3(1024), 0, stream>>>(qvec, qnorm, keys, kn, khi, klo, kmx, fw, pm, w_ws, itop, gain);
  k5_holo<<<dim3(NROWS / 8), dim3(256), 0, stream>>>(hre, him, kf_re, kf_im, w_ws, itop, Grp, Gip, rb, triplet);
  k6_mfma<<<dim3(NROWS / 16), dim3(256), 0, stream>>>(triplet, Wohi, Wolo, bo, go, bbo, gain, out);
}

// Round 12
// 267.219 us; speedup vs baseline: 1.1309x; 1.1309x over previous
//
#include <hip/hip_runtime.h>
#include <hip/hip_bf16.h>
#include <math.h>

#define NROWS 8192
#define INDIM 768
#define TD    72
#define DM    24
#define MKEYS 8192
#define KSEL  32
#define HN    256
#define K3CAND 128

#define TWO_PI_F 6.283185307179586f

typedef __attribute__((ext_vector_type(8))) short short8_t;
typedef __attribute__((ext_vector_type(4))) float f32x4;

__device__ __forceinline__ float gelu_exact(float v){
  return 0.5f * v * (1.0f + erff(v * 0.7071067811865476f));
}

// round-to-nearest-even f32 -> bf16 bits
__device__ __forceinline__ unsigned short bf16rn(float f){
  unsigned u = __float_as_uint(f);
  unsigned r = u + 0x7FFFu + ((u >> 16) & 1u);
  return (unsigned short)(r >> 16);
}

// min across each 16-lane DPP row; lane 15 (mod 16) holds the row min.
__device__ __forceinline__ float rowmin16(float v){
  int s, p;
  s = __float_as_int(v); p = __builtin_amdgcn_update_dpp(s, s, 0x111, 0xF, 0xF, false);
  v = fminf(v, __int_as_float(p));
  s = __float_as_int(v); p = __builtin_amdgcn_update_dpp(s, s, 0x112, 0xF, 0xF, false);
  v = fminf(v, __int_as_float(p));
  s = __float_as_int(v); p = __builtin_amdgcn_update_dpp(s, s, 0x114, 0xF, 0xF, false);
  v = fminf(v, __int_as_float(p));
  s = __float_as_int(v); p = __builtin_amdgcn_update_dpp(s, s, 0x118, 0xF, 0xF, false);
  v = fminf(v, __int_as_float(p));
  return v;
}

// ---------------------------------------------------------------------------
// K0: G = FFT_256(RW[o][0:256] + i*RW[o][256:512]) panels for k5.
// ---------------------------------------------------------------------------
__global__ __launch_bounds__(256) void k0_gprep(
    const float* __restrict__ RW, float* __restrict__ Grp, float* __restrict__ Gip)
{
  __shared__ float sre[16][260];
  __shared__ float sim_[16][260];
  __shared__ float twc[HN], tws[HN];
  const int t = threadIdx.x;
  const int o0 = blockIdx.x * 16;
  {
    const float a = (float)t * (TWO_PI_F / 256.f);
    twc[t] = cosf(a); tws[t] = sinf(a);
  }
  const int r = t >> 4, cg = t & 15;
  const int o = o0 + r;
#pragma unroll
  for (int j = 0; j < 16; j++) {
    const int n = cg + 16 * j;
    const int hb = __brev((unsigned)n) >> 24;
    float cr = 0.f, ci = 0.f;
    if (o < TD) { cr = RW[(size_t)o * 512 + n]; ci = RW[(size_t)o * 512 + 256 + n]; }
    sre[r][hb] = cr; sim_[r][hb] = ci;
  }
  __syncthreads();
  const int t16 = t & 15;
  for (int s = 0; s < 8; s++) {
    const int half = 1 << s;
#pragma unroll
    for (int p = 0; p < 8; p++) {
      const int bi = t16 + 16 * p;
      const int jj = bi & (half - 1);
      const int base = (bi >> s) << (s + 1);
      const int i0 = base + jj, i1 = i0 + half;
      const int tw = jj << (7 - s);
      const float wr = twc[tw], wi = -tws[tw];
      const float ar = sre[r][i0], ai = sim_[r][i0];
      const float br = sre[r][i1], b2 = sim_[r][i1];
      const float tr = wr * br - wi * b2, ti = wr * b2 + wi * br;
      sre[r][i0] = ar + tr; sim_[r][i0] = ai + ti;
      sre[r][i1] = ar - tr; sim_[r][i1] = ai - ti;
    }
    __syncthreads();
  }
#pragma unroll
  for (int p = 0; p < 16; p++) {
    const int h = t16 + 16 * p;
    const size_t base = ((size_t)(h >> 2) * 128 + o) * 4 + (h & 3);
    Grp[base] = sre[r][h];
    Gip[base] = sim_[r][h];
  }
}

// ---------------------------------------------------------------------------
// KW: split key_phase_W (256x768) into bf16 hi/lo panels.
// ---------------------------------------------------------------------------
__global__ __launch_bounds__(256) void kw_split(
    const float* __restrict__ Wp, unsigned short* __restrict__ Wphi,
    unsigned short* __restrict__ Wplo)
{
  const int i4 = blockIdx.x * 256 + threadIdx.x;
  const float4 v = ((const float4*)Wp)[i4];
  float vv[4] = {v.x, v.y, v.z, v.w};
  ushort4 hh, ll;
  unsigned short* hp = (unsigned short*)&hh;
  unsigned short* lp = (unsigned short*)&ll;
#pragma unroll
  for (int j = 0; j < 4; j++) {
    const unsigned short h = bf16rn(vv[j]);
    const float hf = __uint_as_float(((unsigned)h) << 16);
    hp[j] = h; lp[j] = bf16rn(vv[j] - hf);
  }
  ((ushort4*)Wphi)[i4] = hh;
  ((ushort4*)Wplo)[i4] = ll;
}

// ---------------------------------------------------------------------------
// KWO: split W_out (768x72) into zero-padded 768x96 bf16 hi/lo panels.
// ---------------------------------------------------------------------------
__global__ __launch_bounds__(256) void kwo_split(
    const float* __restrict__ Wo, unsigned short* __restrict__ Wohi,
    unsigned short* __restrict__ Wolo)
{
  const int idx = blockIdx.x * 256 + threadIdx.x;   // 768*96 = 73728, grid 288
  const int row = idx / 96, k = idx % 96;
  const float v = (k < TD) ? Wo[(size_t)row * TD + k] : 0.f;
  const unsigned short h = bf16rn(v);
  const float hf = __uint_as_float(((unsigned)h) << 16);
  Wohi[idx] = h;
  Wolo[idx] = bf16rn(v - hf);
}

// ---------------------------------------------------------------------------
// K1 (fp32 — q is SELECTION-CRITICAL: keep this exact fmaf chain).
// ---------------------------------------------------------------------------
__global__ __launch_bounds__(256) void k1_encode(
    const float* __restrict__ x, const float* __restrict__ Wi,
    const float* __restrict__ bi, const float* __restrict__ gi,
    const float* __restrict__ bbi, const float* __restrict__ ricci,
    float* __restrict__ qvec, float* __restrict__ qnorm)
{
  __shared__ float xs[16][132];
  __shared__ float Ws[TD][132];
  __shared__ float zs[16][73];
  __shared__ float zb[16][25];
  const int t = threadIdx.x;
  const int r2 = t >> 4, ks = (t >> 3) & 1, u = t & 7;
  const int row0 = blockIdx.x * 16;

  float acc[9];
#pragma unroll
  for (int j = 0; j < 9; j++) acc[j] = 0.f;

  for (int kc = 0; kc < 6; kc++) {
    __syncthreads();
#pragma unroll
    for (int i = 0; i < 2; i++) {
      int idx = t + 256 * i;
      int rr = idx >> 5, kk = (idx & 31) << 2;
      *(float4*)&xs[rr][kk] = *(const float4*)&x[(size_t)(row0 + rr) * INDIM + kc * 128 + kk];
    }
#pragma unroll
    for (int i = 0; i < 9; i++) {
      int idx = t + 256 * i;
      int rr = idx >> 5, kk = (idx & 31) << 2;
      *(float4*)&Ws[rr][kk] = *(const float4*)&Wi[(size_t)rr * INDIM + kc * 128 + kk];
    }
    __syncthreads();
    const int kb = ks * 64;
#pragma unroll 4
    for (int kq = 0; kq < 16; kq++) {
      const float4 xv = *(const float4*)&xs[r2][kb + kq * 4];
#pragma unroll
      for (int j = 0; j < 9; j++) {
        const float4 wv = *(const float4*)&Ws[u + 8 * j][kb + kq * 4];
        acc[j] = fmaf(xv.x, wv.x, fmaf(xv.y, wv.y, fmaf(xv.z, wv.z, fmaf(xv.w, wv.w, acc[j]))));
      }
    }
  }
#pragma unroll
  for (int j = 0; j < 9; j++) acc[j] += __shfl_xor(acc[j], 8);

  float yv[9];
  float ps = 0.f, pq = 0.f;
#pragma unroll
  for (int j = 0; j < 9; j++) {
    const int o = u + 8 * j;
    yv[j] = acc[j] + bi[o];
    ps += yv[j]; pq += yv[j] * yv[j];
  }
#pragma unroll
  for (int m = 1; m < 8; m <<= 1) { ps += __shfl_xor(ps, m); pq += __shfl_xor(pq, m); }
  const float mean = ps * (1.f / 72.f);
  const float var  = pq * (1.f / 72.f) - mean * mean;
  const float rstd = rsqrtf(var + 1e-5f);
#pragma unroll
  for (int j = 0; j < 9; j++) {
    const int o = u + 8 * j;
    const float z = gelu_exact((yv[j] - mean) * rstd * gi[o] + bbi[o]);
    if (ks == 0) zs[r2][o] = z;
  }
  __syncthreads();
  {
    const int kt = t & 15;
    for (int e = kt; e < 24; e += 16)
      zb[r2][e] = (zs[r2][3 * e] + zs[r2][3 * e + 1] + zs[r2][3 * e + 2]) * (1.f / 3.f);
  }
  __syncthreads();
  {
    const int kt = t & 15;
    float qnp = 0.f;
    for (int d = kt; d < 24; d += 16) {
      float qd = 0.f;
#pragma unroll
      for (int e = 0; e < 24; e++) qd = fmaf(zb[r2][e], ricci[e * 24 + d], qd);
      qvec[(size_t)(row0 + r2) * DM + d] = qd;
      qnp = fmaf(qd, qd, qnp);
    }
#pragma unroll
    for (int m = 1; m < 16; m <<= 1) qnp += __shfl_xor(qnp, m, 16);
    if (kt == 0) qnorm[row0 + r2] = qnp;
  }
}

// ---------------------------------------------------------------------------
// K2: key norms + quantum-phase means + bf16 hi/lo split keys + chunk kn-max
// ---------------------------------------------------------------------------
__global__ __launch_bounds__(256) void k2_prep(
    const float* __restrict__ keys, const float* __restrict__ qp,
    float* __restrict__ kn, float* __restrict__ pm,
    unsigned short* __restrict__ khi, unsigned short* __restrict__ klo,
    float* __restrict__ kmx)
{
  __shared__ float red[256];
  const int t = threadIdx.x;
  const int m = blockIdx.x * 256 + t;
  float kv[24];
#pragma unroll
  for (int d = 0; d < DM; d += 4) {
    const float4 v = *(const float4*)&keys[(size_t)m * DM + d];
    kv[d] = v.x; kv[d + 1] = v.y; kv[d + 2] = v.z; kv[d + 3] = v.w;
  }
  float s = 0.f;
#pragma unroll
  for (int d = 0; d < DM; d++) s = fmaf(kv[d], kv[d], s);
  kn[m] = s;
  float p = 0.f;
#pragma unroll
  for (int q = 0; q < 8; q++) p += tanhf(qp[(size_t)m * 8 + q]);
  pm[m] = p * 0.125f;
#pragma unroll
  for (int d = 0; d < DM; d++) {
    const unsigned short h = bf16rn(kv[d]);
    const float hf = __uint_as_float(((unsigned)h) << 16);
    const unsigned short l = bf16rn(kv[d] - hf);
    khi[(size_t)m * 32 + d] = h;
    klo[(size_t)m * 32 + d] = l;
  }
#pragma unroll
  for (int d = DM; d < 32; d++) { khi[(size_t)m * 32 + d] = 0; klo[(size_t)m * 32 + d] = 0; }
  red[t] = s;
  __syncthreads();
  for (int off = 128; off > 0; off >>= 1) {
    if (t < off) red[t] = fmaxf(red[t], red[t + off]);
    __syncthreads();
  }
  if (t == 0) kmx[blockIdx.x] = red[0];
}

// ---------------------------------------------------------------------------
// K3 v8: round-9 v5 structure (32 rows, 2 row-tiles, grid 256) + ROLLING
// depth-4 register prefetch (peak live ~5 load-sets ~45 extra VGPRs, fits
// the 128-VGPR cap of (1024,4); v6's depth-8 needed ~136 -> spilled).
// Each d2a value computed by the identical MFMA chain; min/filter are
// order-independent -> identical selection -> identical output.
// ---------------------------------------------------------------------------
__global__ __launch_bounds__(1024, 4) void k3_topk(
    const float* __restrict__ qvec, const float* __restrict__ qnorm,
    const float* __restrict__ keys, const float* __restrict__ kn,
    const unsigned short* __restrict__ khi, const unsigned short* __restrict__ klo,
    const float* __restrict__ kmx,
    const float* __restrict__ fw,  const float* __restrict__ pm,
    float* __restrict__ w_out, int* __restrict__ itop_out, float* __restrict__ gain_out)
{
  __shared__ float qsm[32][25];
  __shared__ float qns[32];
  __shared__ unsigned short qh_l[32][32];
  __shared__ unsigned short ql_l[32][32];
  __shared__ float gmins[64][33];
  __shared__ float Ts[32];
  __shared__ float Tm2s[32];
  __shared__ unsigned glive[2];
  __shared__ int cnt[32];
  __shared__ int      candI[32][K3CAND];
  __shared__ unsigned candV[32][K3CAND];
  __shared__ float wV[32][KSEL];
  __shared__ int   wI[32][KSEL];
  __shared__ float knmax_s;

  const int t = threadIdx.x;
  const int w = t >> 6, lane = t & 63;
  const int colid = lane & 15;
  const int kgrp  = lane >> 4;
  const int row0 = blockIdx.x * 32;

  if (t < 32 * DM) qsm[t / DM][t % DM] = qvec[(size_t)row0 * DM + t];
  if (t < 32) { qns[t] = qnorm[row0 + t]; cnt[t] = 0; }
  if (t < 2) glive[t] = 0u;
  if (t == 0) { float m = 0.f; for (int i = 0; i < 32; i++) m = fmaxf(m, kmx[i]); knmax_s = m; }
  __syncthreads();
  {
    const int r = t >> 5, k = t & 31;
    const float v = (k < DM) ? qsm[r][k] : 0.f;
    const unsigned short h = bf16rn(v);
    const float hf = __uint_as_float(((unsigned)h) << 16);
    qh_l[r][k] = h;
    ql_l[r][k] = bf16rn(v - hf);
  }
  __syncthreads();

  const short8_t ah0 = *(const short8_t*)&qh_l[colid][kgrp * 8];
  const short8_t al0 = *(const short8_t*)&ql_l[colid][kgrp * 8];
  const short8_t ah1 = *(const short8_t*)&qh_l[16 + colid][kgrp * 8];
  const short8_t al1 = *(const short8_t*)&ql_l[16 + colid][kgrp * 8];
  float qn8[8];
#pragma unroll
  for (int reg = 0; reg < 4; reg++) {
    qn8[reg]     = qns[kgrp * 4 + reg];
    qn8[reg + 4] = qns[16 + kgrp * 4 + reg];
  }

  // ---- pass A: approx group minima, rolling depth-4 prefetch ----
  for (int u = 0; u < 4; u++) {
    const int g = w + 16 * u;
    const int nbase = g * 128;
    short8_t pbh[4], pbl[4];
    float pkn[4];
#pragma unroll
    for (int j = 0; j < 4; j++) {
      const int key = nbase + j * 16 + colid;
      pbh[j] = *(const short8_t*)&khi[(size_t)key * 32 + kgrp * 8];
      pbl[j] = *(const short8_t*)&klo[(size_t)key * 32 + kgrp * 8];
      pkn[j] = kn[key];
    }
    float mn[8];
#pragma unroll
    for (int j = 0; j < 8; j++) {
      const int slot = j & 3;
      const short8_t bh = pbh[slot];
      const short8_t bl = pbl[slot];
      const float knv = pkn[slot];
      if (j < 4) {
        const int key = nbase + (j + 4) * 16 + colid;
        pbh[slot] = *(const short8_t*)&khi[(size_t)key * 32 + kgrp * 8];
        pbl[slot] = *(const short8_t*)&klo[(size_t)key * 32 + kgrp * 8];
        pkn[slot] = kn[key];
      }
      f32x4 c0 = {0.f, 0.f, 0.f, 0.f}, c1 = {0.f, 0.f, 0.f, 0.f};
      c0 = __builtin_amdgcn_mfma_f32_16x16x32_bf16(ah0, bh, c0, 0, 0, 0);
      c1 = __builtin_amdgcn_mfma_f32_16x16x32_bf16(ah1, bh, c1, 0, 0, 0);
      c0 = __builtin_amdgcn_mfma_f32_16x16x32_bf16(ah0, bl, c0, 0, 0, 0);
      c1 = __builtin_amdgcn_mfma_f32_16x16x32_bf16(ah1, bl, c1, 0, 0, 0);
      c0 = __builtin_amdgcn_mfma_f32_16x16x32_bf16(al0, bh, c0, 0, 0, 0);
      c1 = __builtin_amdgcn_mfma_f32_16x16x32_bf16(al1, bh, c1, 0, 0, 0);
#pragma unroll
      for (int reg = 0; reg < 4; reg++) {
        const float d0 = fmaf(-2.f, c0[reg], qn8[reg] + knv);
        const float d1 = fmaf(-2.f, c1[reg], qn8[reg + 4] + knv);
        if (j == 0) { mn[reg] = d0; mn[reg + 4] = d1; }
        else        { mn[reg] = fminf(mn[reg], d0); mn[reg + 4] = fminf(mn[reg + 4], d1); }
      }
    }
#pragma unroll
    for (int reg = 0; reg < 4; reg++) {
      const float v0 = rowmin16(mn[reg]);
      const float v1 = rowmin16(mn[reg + 4]);
      if (colid == 15) {
        gmins[g][kgrp * 4 + reg] = v0;
        gmins[g][16 + kgrp * 4 + reg] = v1;
      }
    }
  }
  __syncthreads();

  {
    const int r = t & 31, i = t >> 5;
    const float v0 = gmins[i * 2][r], v1 = gmins[i * 2 + 1][r];
    int rk0 = 0, eq0 = 0, rk1 = 0, eq1 = 0;
    for (int g = 0; g < 64; g++) {
      const float gv = gmins[g][r];
      rk0 += (gv < v0); eq0 += (gv == v0);
      rk1 += (gv < v1); eq1 += (gv == v1);
    }
    if (rk0 <= 31 && rk0 + eq0 > 31) Ts[r] = v0;
    if (rk1 <= 31 && rk1 + eq1 > 31) Ts[r] = v1;
  }
  __syncthreads();
  if (t < 32) {
    const float T = Ts[t];
    const float mu = 2e-4f * sqrtf(fmaxf(qns[t], 0.f) * knmax_s) + 1e-6f;
    Tm2s[t] = T + fabsf(T) * 1e-6f + 2.f * mu;
  }
  __syncthreads();
  {
    const int r = t & 31, i = t >> 5;
    const unsigned b0 = (gmins[i * 2][r]     <= Tm2s[r]) ? 1u : 0u;
    const unsigned b1 = (gmins[i * 2 + 1][r] <= Tm2s[r]) ? 2u : 0u;
    const unsigned bits = (b0 | b1) << ((i * 2) & 31);
    if (bits) atomicOr(&glive[i >> 4], bits);
  }
  __syncthreads();

  float tm8[8];
#pragma unroll
  for (int reg = 0; reg < 4; reg++) {
    tm8[reg]     = Tm2s[kgrp * 4 + reg];
    tm8[reg + 4] = Tm2s[16 + kgrp * 4 + reg];
  }

  // ---- pass B: live groups, rolling depth-4 prefetch, candidate filter ----
  for (int u = 0; u < 4; u++) {
    const int g = w + 16 * u;
    if (!((glive[g >> 5] >> (g & 31)) & 1u)) continue;
    const int nbase = g * 128;
    short8_t pbh[4], pbl[4];
    float pkn[4];
#pragma unroll
    for (int j = 0; j < 4; j++) {
      const int key = nbase + j * 16 + colid;
      pbh[j] = *(const short8_t*)&khi[(size_t)key * 32 + kgrp * 8];
      pbl[j] = *(const short8_t*)&klo[(size_t)key * 32 + kgrp * 8];
      pkn[j] = kn[key];
    }
#pragma unroll
    for (int j = 0; j < 8; j++) {
      const int slot = j & 3;
      const short8_t bh = pbh[slot];
      const short8_t bl = pbl[slot];
      const float knv = pkn[slot];
      if (j < 4) {
        const int key = nbase + (j + 4) * 16 + colid;
        pbh[slot] = *(const short8_t*)&khi[(size_t)key * 32 + kgrp * 8];
        pbl[slot] = *(const short8_t*)&klo[(size_t)key * 32 + kgrp * 8];
        pkn[slot] = kn[key];
      }
      const int key = nbase + j * 16 + colid;
      f32x4 c0 = {0.f, 0.f, 0.f, 0.f}, c1 = {0.f, 0.f, 0.f, 0.f};
      c0 = __builtin_amdgcn_mfma_f32_16x16x32_bf16(ah0, bh, c0, 0, 0, 0);
      c1 = __builtin_amdgcn_mfma_f32_16x16x32_bf16(ah1, bh, c1, 0, 0, 0);
      c0 = __builtin_amdgcn_mfma_f32_16x16x32_bf16(ah0, bl, c0, 0, 0, 0);
      c1 = __builtin_amdgcn_mfma_f32_16x16x32_bf16(ah1, bl, c1, 0, 0, 0);
      c0 = __builtin_amdgcn_mfma_f32_16x16x32_bf16(al0, bh, c0, 0, 0, 0);
      c1 = __builtin_amdgcn_mfma_f32_16x16x32_bf16(al1, bh, c1, 0, 0, 0);
#pragma unroll
      for (int reg = 0; reg < 4; reg++) {
        const float d0 = fmaf(-2.f, c0[reg], qn8[reg] + knv);
        if (d0 <= tm8[reg]) {
          const int row = kgrp * 4 + reg;
          const int pos = atomicAdd(&cnt[row], 1);
          if (pos < K3CAND) candI[row][pos] = key;
        }
        const float d1 = fmaf(-2.f, c1[reg], qn8[reg + 4] + knv);
        if (d1 <= tm8[reg + 4]) {
          const int row = 16 + kgrp * 4 + reg;
          const int pos = atomicAdd(&cnt[row], 1);
          if (pos < K3CAND) candI[row][pos] = key;
        }
      }
    }
  }
  for (int idx = t; idx < 32 * KSEL; idx += 1024) { wV[idx >> 5][idx & 31] = 1e30f; wI[idx >> 5][idx & 31] = 0; }
  __syncthreads();

  {
    const int r = t >> 5, kt = t & 31;
    const int C = min(cnt[r], K3CAND);
    const float qnr = qns[r];
    for (int ci = kt; ci < C; ci += 32) {
      const int key = candI[r][ci];
      float kv[24];
#pragma unroll
      for (int d = 0; d < DM; d += 4) {
        const float4 v = *(const float4*)&keys[(size_t)key * DM + d];
        kv[d] = v.x; kv[d + 1] = v.y; kv[d + 2] = v.z; kv[d + 3] = v.w;
      }
      float dot = 0.f;
#pragma unroll
      for (int d = 0; d < DM; d++) dot = fmaf(kv[d], qsm[r][d], dot);
      const float d2 = fmaf(-2.f, dot, qnr + kn[key]);
      candV[r][ci] = __float_as_uint(fmaxf(d2, 0.f));
    }
  }
  __syncthreads();

  {
    const int r = t >> 5, kt = t & 31;
    const int C = min(cnt[r], K3CAND);
    for (int ci = kt; ci < C; ci += 32) {
      const unsigned v = candV[r][ci];
      const unsigned key = (unsigned)candI[r][ci];
      int rk = 0;
      for (int j = 0; j < C; j++) {
        const unsigned vj = candV[r][j];
        rk += (vj < v) || (vj == v && (unsigned)candI[r][j] < key);
      }
      if (rk < KSEL) { wV[r][rk] = __uint_as_float(v); wI[r][rk] = (int)key; }
    }
  }
  __syncthreads();

  float sc;
  {
    const float f0 = fw[0], f1 = fw[1], f2 = fw[2], f3 = fw[3];
    const float mx = fmaxf(fmaxf(f0, f1), fmaxf(f2, f3));
    const float e0 = expf(f0 - mx), e1 = expf(f1 - mx), e2 = expf(f2 - mx), e3 = expf(f3 - mx);
    sc = (e0 + 0.5f * e1 + 0.25f * e2 + 0.125f * e3) / (e0 + e1 + e2 + e3);
  }
  if (t < 512) {
    const int r = t >> 4, kt = t & 15;
    const float dA = sqrtf(wV[r][kt]) * sc;
    const float dB = sqrtf(wV[r][kt + 16]) * sc;
    float mn = fminf(dA, dB);
#pragma unroll
    for (int m = 1; m < 16; m <<= 1) mn = fminf(mn, __shfl_xor(mn, m, 16));
    const float eA = expf(mn - dA), eB = expf(mn - dB);
    float s = eA + eB;
#pragma unroll
    for (int m = 1; m < 16; m <<= 1) s += __shfl_xor(s, m, 16);
    const float w0 = eA / s, w1 = eB / s;
    const int k0 = wI[r][kt], k1 = wI[r][kt + 16];
    float gp = w0 * pm[k0] + w1 * pm[k1];
#pragma unroll
    for (int m = 1; m < 16; m <<= 1) gp += __shfl_xor(gp, m, 16);
    const size_t row = (size_t)(row0 + r);
    w_out[row * KSEL + kt] = w0;      w_out[row * KSEL + kt + 16] = w1;
    itop_out[row * KSEL + kt] = k0;   itop_out[row * KSEL + kt + 16] = k1;
    if (kt == 0) gain_out[row] = 1.f + 0.02f * gp;
  }
}

// ---------------------------------------------------------------------------
// K4a: p = x@Wp.T + bp via MFMA. (unchanged)
// ---------------------------------------------------------------------------
__global__ __launch_bounds__(512) void k4a_pgemm(
    const float* __restrict__ x, const unsigned short* __restrict__ Wphi,
    const unsigned short* __restrict__ Wplo, const float* __restrict__ bp,
    float* __restrict__ p)
{
  const int t = threadIdx.x;
  const int w = t >> 6, lane = t & 63;
  const int colid = lane & 15, kgrp = lane >> 4;
  const int wm = w >> 2, wn = w & 3;
  const int row0 = blockIdx.x * 32;
  const int arow = row0 + wm * 16 + colid;

  f32x4 acc0 = {0.f, 0.f, 0.f, 0.f};
  f32x4 acc1 = {0.f, 0.f, 0.f, 0.f};
  f32x4 acc2 = {0.f, 0.f, 0.f, 0.f};
  f32x4 acc3 = {0.f, 0.f, 0.f, 0.f};

  for (int kc = 0; kc < 24; kc++) {
    const int kb = kc * 32 + kgrp * 8;
    float xv[8];
    *(float4*)&xv[0] = *(const float4*)&x[(size_t)arow * INDIM + kb];
    *(float4*)&xv[4] = *(const float4*)&x[(size_t)arow * INDIM + kb + 4];
    short8_t ah, al;
#pragma unroll
    for (int i = 0; i < 8; i++) {
      const unsigned short h = bf16rn(xv[i]);
      const float hf = __uint_as_float(((unsigned)h) << 16);
      ah[i] = (short)h;
      al[i] = (short)bf16rn(xv[i] - hf);
    }
#pragma unroll
    for (int ct = 0; ct < 4; ct++) {
      const int col = wn * 64 + ct * 16 + colid;
      const short8_t bh = *(const short8_t*)&Wphi[(size_t)col * INDIM + kb];
      const short8_t bl = *(const short8_t*)&Wplo[(size_t)col * INDIM + kb];
      f32x4* pa = (ct == 0) ? &acc0 : (ct == 1) ? &acc1 : (ct == 2) ? &acc2 : &acc3;
      *pa = __builtin_amdgcn_mfma_f32_16x16x32_bf16(ah, bh, *pa, 0, 0, 0);
      *pa = __builtin_amdgcn_mfma_f32_16x16x32_bf16(al, bh, *pa, 0, 0, 0);
      *pa = __builtin_amdgcn_mfma_f32_16x16x32_bf16(ah, bl, *pa, 0, 0, 0);
    }
  }
#pragma unroll
  for (int ct = 0; ct < 4; ct++) {
    const int col = wn * 64 + ct * 16 + colid;
    const float b = bp[col];
    const f32x4 a = (ct == 0) ? acc0 : (ct == 1) ? acc1 : (ct == 2) ? acc2 : acc3;
#pragma unroll
    for (int reg = 0; reg < 4; reg++) {
      const int row = row0 + wm * 16 + kgrp * 4 + reg;
      p[(size_t)row * HN + col] = a[reg] + b;
    }
  }
}

// ---------------------------------------------------------------------------
// K4b: Kf = FFT(e^{i 2pi sigmoid(p)}) * e^{i ek}. (unchanged)
// ---------------------------------------------------------------------------
__global__ __launch_bounds__(256) void k4b_fft(
    const float* __restrict__ p, const float* __restrict__ ek,
    float* __restrict__ kf_re, float* __restrict__ kf_im)
{
  __shared__ float2 c[16][273];
  __shared__ float twc[HN], tws[HN];
  const int t = threadIdx.x;
  const int row0 = blockIdx.x * 16;
  {
    const float a = (float)t * (TWO_PI_F / 256.f);
    twc[t] = cosf(a); tws[t] = sinf(a);
  }
  {
    const int hb = __brev((unsigned)t) >> 24;
    const int hbi = hb + (hb >> 5);
#pragma unroll
    for (int i = 0; i < 16; i++) {
      const float pv = p[(size_t)(row0 + i) * HN + t];
      const float sg = 1.f / (1.f + expf(-pv));
      float sn, cs;
      __sincosf(TWO_PI_F * sg, &sn, &cs);
      c[i][hbi] = make_float2(cs, sn);
    }
  }
  __syncthreads();
  const int r = t >> 4, t16 = t & 15;
  for (int s = 0; s < 8; s++) {
    const int half = 1 << s;
#pragma unroll
    for (int pp = 0; pp < 8; pp++) {
      const int bi = t16 + 16 * pp;
      const int jj = bi & (half - 1);
      const int base = (bi >> s) << (s + 1);
      const int i0 = base + jj, i1 = i0 + half;
      const int tw = jj << (7 - s);
      const float wr = twc[tw], wi = -tws[tw];
      const int p0 = i0 + (i0 >> 5), p1 = i1 + (i1 >> 5);
      const float2 A = c[r][p0];
      const float2 B = c[r][p1];
      const float tr = wr * B.x - wi * B.y, ti = wr * B.y + wi * B.x;
      c[r][p0] = make_float2(A.x + tr, A.y + ti);
      c[r][p1] = make_float2(A.x - tr, A.y - ti);
    }
    __syncthreads();
  }
  {
    float esn, ecs;
    __sincosf(ek[t], &esn, &ecs);
    const int ti = t + (t >> 5);
#pragma unroll
    for (int i = 0; i < 16; i++) {
      const float2 v = c[i][ti];
      const size_t o = (size_t)(row0 + i) * HN + t;
      kf_re[o] = v.x * ecs - v.y * esn;
      kf_im[o] = v.x * esn + v.y * ecs;
    }
  }
}

// ---------------------------------------------------------------------------
// K5 v2: gather + Y = conj(Kf)*Hmix, then triplet = rb + (Y . G)/256. (unchanged)
// ---------------------------------------------------------------------------
__global__ __launch_bounds__(256) void k5_holo(
    const float* __restrict__ holo_re, const float* __restrict__ holo_im,
    const float* __restrict__ kf_re, const float* __restrict__ kf_im,
    const float* __restrict__ w_ws, const int* __restrict__ itop_ws,
    const float* __restrict__ Grp, const float* __restrict__ Gip,
    const float* __restrict__ rb, float* __restrict__ triplet)
{
  __shared__ __align__(16) float ysr[8][260];
  __shared__ __align__(16) float ysi[8][260];
  __shared__ float red[4][8][128];
  __shared__ float wsm[8][KSEL];
  __shared__ int   ism[8][KSEL];
  const int t = threadIdx.x;
  const int w = t >> 6, lane = t & 63;
  const int row0 = blockIdx.x * 8;

  {
    const int rr = t >> 5, k2 = t & 31;
    wsm[rr][k2] = w_ws[(size_t)(row0 + rr) * KSEL + k2];
    ism[rr][k2] = itop_ws[(size_t)(row0 + rr) * KSEL + k2];
  }
  __syncthreads();

#pragma unroll
  for (int pass = 0; pass < 2; pass++) {
    const int row = w + 4 * pass;
    float4 hr4 = {0.f, 0.f, 0.f, 0.f};
    float4 hi4 = {0.f, 0.f, 0.f, 0.f};
#pragma unroll 8
    for (int k2 = 0; k2 < KSEL; k2++) {
      const int m = ism[row][k2];
      const float wk = wsm[row][k2];
      const float4 re4 = *(const float4*)&holo_re[(size_t)m * HN + lane * 4];
      const float4 im4 = *(const float4*)&holo_im[(size_t)m * HN + lane * 4];
      hr4.x = fmaf(wk, re4.x, hr4.x); hr4.y = fmaf(wk, re4.y, hr4.y);
      hr4.z = fmaf(wk, re4.z, hr4.z); hr4.w = fmaf(wk, re4.w, hr4.w);
      hi4.x = fmaf(wk, im4.x, hi4.x); hi4.y = fmaf(wk, im4.y, hi4.y);
      hi4.z = fmaf(wk, im4.z, hi4.z); hi4.w = fmaf(wk, im4.w, hi4.w);
    }
    const size_t o = (size_t)(row0 + row) * HN + lane * 4;
    const float4 kr4 = *(const float4*)&kf_re[o];
    const float4 ki4 = *(const float4*)&kf_im[o];
    float4 yr4, yi4;
    yr4.x = kr4.x * hr4.x + ki4.x * hi4.x;  yi4.x = kr4.x * hi4.x - ki4.x * hr4.x;
    yr4.y = kr4.y * hr4.y + ki4.y * hi4.y;  yi4.y = kr4.y * hi4.y - ki4.y * hr4.y;
    yr4.z = kr4.z * hr4.z + ki4.z * hi4.z;  yi4.z = kr4.z * hi4.z - ki4.z * hr4.z;
    yr4.w = kr4.w * hr4.w + ki4.w * hi4.w;  yi4.w = kr4.w * hi4.w - ki4.w * hr4.w;
    *(float4*)&ysr[row][lane * 4] = yr4;
    *(float4*)&ysi[row][lane * 4] = yi4;
  }
  __syncthreads();

  float acc[8][2];
#pragma unroll
  for (int rr = 0; rr < 8; rr++) { acc[rr][0] = 0.f; acc[rr][1] = 0.f; }
#pragma unroll 4
  for (int i = 0; i < 16; i++) {
    const int h4 = w * 16 + i;
    const float4 gra = *(const float4*)&Grp[((size_t)h4 * 128 + lane) * 4];
    const float4 gia = *(const float4*)&Gip[((size_t)h4 * 128 + lane) * 4];
    const float4 grb = *(const float4*)&Grp[((size_t)h4 * 128 + 64 + lane) * 4];
    const float4 gib = *(const float4*)&Gip[((size_t)h4 * 128 + 64 + lane) * 4];
#pragma unroll
    for (int rr = 0; rr < 8; rr++) {
      const float4 yr4 = *(const float4*)&ysr[rr][h4 * 4];
      const float4 yi4 = *(const float4*)&ysi[rr][h4 * 4];
      acc[rr][0] = fmaf(yr4.x, gra.x, fmaf(yr4.y, gra.y, fmaf(yr4.z, gra.z, fmaf(yr4.w, gra.w, acc[rr][0]))));
      acc[rr][0] = fmaf(yi4.x, gia.x, fmaf(yi4.y, gia.y, fmaf(yi4.z, gia.z, fmaf(yi4.w, gia.w, acc[rr][0]))));
      acc[rr][1] = fmaf(yr4.x, grb.x, fmaf(yr4.y, grb.y, fmaf(yr4.z, grb.z, fmaf(yr4.w, grb.w, acc[rr][1]))));
      acc[rr][1] = fmaf(yi4.x, gib.x, fmaf(yi4.y, gib.y, fmaf(yi4.z, gib.z, fmaf(yi4.w, gib.w, acc[rr][1]))));
    }
  }
#pragma unroll
  for (int rr = 0; rr < 8; rr++) {
    red[w][rr][lane] = acc[rr][0];
    red[w][rr][64 + lane] = acc[rr][1];
  }
  __syncthreads();

  for (int idx = t; idx < 8 * 128; idx += 256) {
    const int rr = idx >> 7, o = idx & 127;
    if (o < TD) {
      const float s = red[0][rr][o] + red[1][rr][o] + red[2][rr][o] + red[3][rr][o];
      triplet[(size_t)(row0 + rr) * TD + o] = rb[o] + s * (1.f / 256.f);
    }
  }
}

// ---------------------------------------------------------------------------
// K6 v2 (MFMA): out = gelu(LN(triplet@W_out.T + b_out)) * gain. (unchanged)
// ---------------------------------------------------------------------------
__global__ __launch_bounds__(256) void k6_mfma(
    const float* __restrict__ triplet, const unsigned short* __restrict__ Wohi,
    const unsigned short* __restrict__ Wolo, const float* __restrict__ bo,
    const float* __restrict__ go, const float* __restrict__ bbo,
    const float* __restrict__ gain, float* __restrict__ out)
{
  __shared__ float ys[16][772];
  const int t = threadIdx.x;
  const int w = t >> 6, lane = t & 63;
  const int colid = lane & 15, kgrp = lane >> 4;
  const int row0 = blockIdx.x * 16;
  const int arow = row0 + colid;

  f32x4 acc[12];
#pragma unroll
  for (int ct = 0; ct < 12; ct++) acc[ct] = (f32x4){0.f, 0.f, 0.f, 0.f};

#pragma unroll
  for (int kc = 0; kc < 3; kc++) {
    const int kb = kc * 32 + kgrp * 8;
    float xv[8];
    if (kb < TD) {
      *(float4*)&xv[0] = *(const float4*)&triplet[(size_t)arow * TD + kb];
      *(float4*)&xv[4] = *(const float4*)&triplet[(size_t)arow * TD + kb + 4];
    } else {
#pragma unroll
      for (int i = 0; i < 8; i++) xv[i] = 0.f;
    }
    short8_t ah, al;
#pragma unroll
    for (int i = 0; i < 8; i++) {
      const unsigned short h = bf16rn(xv[i]);
      const float hf = __uint_as_float(((unsigned)h) << 16);
      ah[i] = (short)h; al[i] = (short)bf16rn(xv[i] - hf);
    }
#pragma unroll
    for (int ct = 0; ct < 12; ct++) {
      const int col = w * 192 + ct * 16 + colid;
      const short8_t bh = *(const short8_t*)&Wohi[(size_t)col * 96 + kb];
      const short8_t bl = *(const short8_t*)&Wolo[(size_t)col * 96 + kb];
      acc[ct] = __builtin_amdgcn_mfma_f32_16x16x32_bf16(ah, bh, acc[ct], 0, 0, 0);
      acc[ct] = __builtin_amdgcn_mfma_f32_16x16x32_bf16(al, bh, acc[ct], 0, 0, 0);
      acc[ct] = __builtin_amdgcn_mfma_f32_16x16x32_bf16(ah, bl, acc[ct], 0, 0, 0);
    }
  }
#pragma unroll
  for (int ct = 0; ct < 12; ct++) {
    const int col = w * 192 + ct * 16 + colid;
    const float b = bo[col];
#pragma unroll
    for (int reg = 0; reg < 4; reg++)
      ys[kgrp * 4 + reg][col] = acc[ct][reg] + b;
  }
  __syncthreads();

  const int r = t >> 4, kt = t & 15;
  float s = 0.f, sq = 0.f;
  for (int u = 0; u < 48; u++) {
    const float v = ys[r][kt + 16 * u];
    s += v; sq = fmaf(v, v, sq);
  }
#pragma unroll
  for (int m = 1; m < 16; m <<= 1) { s += __shfl_xor(s, m, 16); sq += __shfl_xor(sq, m, 16); }
  const float mean = s * (1.f / 768.f);
  const float var  = sq * (1.f / 768.f) - mean * mean;
  const float rstd = rsqrtf(var + 1e-5f);
  const float gn = gain[row0 + r];
  for (int u = 0; u < 48; u++) {
    const int e = kt + 16 * u;
    const float v = (ys[r][e] - mean) * rstd * go[e] + bbo[e];
    out[(size_t)(row0 + r) * INDIM + e] = gelu_exact(v) * gn;
  }
}

// ---------------------------------------------------------------------------
extern "C" void kernel_launch(void* const* d_in, const int* in_sizes, int n_in,
                              void* d_out, int out_size, void* d_ws, size_t ws_size,
                              hipStream_t stream)
{
  (void)in_sizes; (void)n_in; (void)out_size; (void)ws_size;
  const float* x     = (const float*)d_in[0];
  const float* Wi    = (const float*)d_in[1];
  const float* bi    = (const float*)d_in[2];
  const float* gi    = (const float*)d_in[3];
  const float* bbi   = (const float*)d_in[4];
  const float* ricci = (const float*)d_in[5];
  const float* fw    = (const float*)d_in[6];
  const float* keys  = (const float*)d_in[7];
  const float* Wp    = (const float*)d_in[8];
  const float* bp    = (const float*)d_in[9];
  const float* ek    = (const float*)d_in[10];
  const float* hre   = (const float*)d_in[11];
  const float* him   = (const float*)d_in[12];
  const float* RW    = (const float*)d_in[13];
  const float* rb    = (const float*)d_in[14];
  const float* Wo    = (const float*)d_in[15];
  const float* bo    = (const float*)d_in[16];
  const float* go    = (const float*)d_in[17];
  const float* bbo   = (const float*)d_in[18];
  const float* qp    = (const float*)d_in[19];
  float* out = (float*)d_out;

  char* ws = (char*)d_ws;
  float* qvec    = (float*)(ws + 0);
  float* qnorm   = (float*)(ws + 786432);
  float* kn      = (float*)(ws + 819200);
  float* pm      = (float*)(ws + 851968);
  float* gain    = (float*)(ws + 884736);
  float* w_ws    = (float*)(ws + 917504);
  int*   itop    = (int*)  (ws + 1966080);
  float* triplet = (float*)(ws + 3014656);
  float* kf_re   = (float*)(ws + 5373952);
  float* kf_im   = (float*)(ws + 13762560);
  unsigned short* khi = (unsigned short*)(ws + 22151168);  // 524288
  unsigned short* klo = (unsigned short*)(ws + 22675456);  // 524288
  float* kmx     = (float*)(ws + 23199744);                // 1 KB
  float* Grp     = (float*)(ws + 23200768);                // 131072
  float* Gip     = (float*)(ws + 23331840);                // 131072
  unsigned short* Wphi = (unsigned short*)(ws + 23462912); // 393216
  unsigned short* Wplo = (unsigned short*)(ws + 23856128); // 393216
  float* pbuf    = (float*)(ws + 24249344);                // 8388608
  unsigned short* Wohi = (unsigned short*)(ws + 32637952); // 147456
  unsigned short* Wolo = (unsigned short*)(ws + 32785408); // 147456 -> ends 32932864

  k0_gprep<<<dim3(8), dim3(256), 0, stream>>>(RW, Grp, Gip);
  kw_split<<<dim3(192), dim3(256), 0, stream>>>(Wp, Wphi, Wplo);
  kwo_split<<<dim3(288), dim3(256), 0, stream>>>(Wo, Wohi, Wolo);
  k2_prep<<<dim3(MKEYS / 256), dim3(256), 0, stream>>>(keys, qp, kn, pm, khi, klo, kmx);
  k1_encode<<<dim3(NROWS / 16), dim3(256), 0, stream>>>(x, Wi, bi, gi, bbi, ricci, qvec, qnorm);
  k4a_pgemm<<<dim3(NROWS / 32), dim3(512), 0, stream>>>(x, Wphi, Wplo, bp, pbuf);
  k4b_fft<<<dim3(NROWS / 16), dim3(256), 0, stream>>>(pbuf, ek, kf_re, kf_im);
  k3_topk<<<dim3(NROWS / 32), dim3(1024), 0, stream>>>(qvec, qnorm, keys, kn, khi, klo, kmx, fw, pm, w_ws, itop, gain);
  k5_holo<<<dim3(NROWS / 8), dim3(256), 0, stream>>>(hre, him, kf_re, kf_im, w_ws, itop, Grp, Gip, rb, triplet);
  k6_mfma<<<dim3(NROWS / 16), dim3(256), 0, stream>>>(triplet, Wohi, Wolo, bo, go, bbo, gain, out);
}